// Round 13
// baseline (185.396 us; speedup 1.0000x reference)
//
#include <hip/hip_runtime.h>
#include <hip/hip_fp16.h>

#define N_NODES 50000
#define N_EDGES 800000
#define BN_EPS 1e-5f

#define NBUCK 196        // ceil(50000/256) buckets of 256 nodes
#define PART_CAP 6016    // per-bucket raw capacity; mean 4082, sd 64 -> 30 sigma margin
#define BUCK_STRIDE 1800 // per-bucket pad allowance: 256 nodes * 7 max pad, 8-aligned, +slack
#define CSR_LDS_CAP 7808 // PART_CAP + 256*7
#define PAD_IDX 50000    // dummy src index -> zero row appended to each gather table
#define PB 196           // partition blocks (ceil(800000/4096))
#define GB 782           // gemm0 blocks (ceil(50000/64), 64-row tiles)

// exclusive WIDTH-thread scan in LDS; s[] is scratch (WIDTH ints). All WIDTH threads call.
// After return, s[WIDTH-1] holds the inclusive total (valid until s is rewritten).
template <int WIDTH>
__device__ __forceinline__ int lds_scan_excl(int* s, int t, int v) {
    s[t] = v;
    __syncthreads();
    for (int off = 1; off < WIDTH; off <<= 1) {
        int x = (t >= off) ? s[t - off] : 0;
        __syncthreads();
        s[t] += x;
        __syncthreads();
    }
    return s[t] - v;
}

// phase of a source node id (4 ranges of 12500); exact floor(s/12500) for s<50000
__device__ __forceinline__ unsigned src_phase(unsigned s) {
    return (s * 42950u) >> 29;
}

// issue 8 row loads (16B each) for the 8 indices packed in iv
template <int LD>
__device__ __forceinline__ void issue8(const __half* __restrict__ T, uint4 iv, int c8,
                                       uint4* vv) {
    int s0 = iv.x & 0xffff, s1 = iv.x >> 16;
    int s2 = iv.y & 0xffff, s3 = iv.y >> 16;
    int s4 = iv.z & 0xffff, s5 = iv.z >> 16;
    int s6 = iv.w & 0xffff, s7 = iv.w >> 16;
    vv[0] = *(const uint4*)&T[(size_t)s0 * LD + c8];
    vv[1] = *(const uint4*)&T[(size_t)s1 * LD + c8];
    vv[2] = *(const uint4*)&T[(size_t)s2 * LD + c8];
    vv[3] = *(const uint4*)&T[(size_t)s3 * LD + c8];
    vv[4] = *(const uint4*)&T[(size_t)s4 * LD + c8];
    vv[5] = *(const uint4*)&T[(size_t)s5 * LD + c8];
    vv[6] = *(const uint4*)&T[(size_t)s6 * LD + c8];
    vv[7] = *(const uint4*)&T[(size_t)s7 * LD + c8];
}

__device__ __forceinline__ void acc8(const uint4* vv, float* acc) {
#pragma unroll
    for (int q = 0; q < 8; ++q) {
        union { uint4 u; __half2 h[4]; } V; V.u = vv[q];
#pragma unroll
        for (int p = 0; p < 4; ++p) {
            float2 f = __half22float2(V.h[p]);
            acc[2 * p] += f.x; acc[2 * p + 1] += f.y;
        }
    }
}

// ---------------- GEMM body: Hs[r,M] = X[r,K] @ (W .* foldscale[c]) ----------------
// 64-row tile; 256 threads = 16x16, each 4x4; K chunked by 32. (proven shape: 978-block
// grid keeps ~4 blocks/CU. 8x8/256-row variant: 76us @ 8% VALUBusy, parallelism collapse.
// r6 mega-fusion: regalloc collapse -> 40 VGPR + 250MB scratch spill, 944us. Keep split.)
template <int K, int M, bool FOLD>
__device__ __forceinline__ void gemm_body(int bid, const float* __restrict__ X,
                                          const float* __restrict__ W,
                                          const float* __restrict__ gamma,
                                          const float* __restrict__ var,
                                          float* __restrict__ Hs, int n, float* lds) {
    constexpr int KC = 32;
    float* Xs = lds;                    // 64 x 36
    float* Ws = lds + 64 * 36;          // 32 x M
    float* bns = lds + 64 * 36 + 32 * M; // M bn scales
    int tid = threadIdx.x;
    int tx = tid & 15, ty = tid >> 4;
    int row0 = bid * 64;
    if (FOLD && tid < M) bns[tid] = gamma[tid] * rsqrtf(var[tid] + BN_EPS);
    __syncthreads();
    float acc[4][4] = {};
    for (int k0 = 0; k0 < K; k0 += KC) {
#pragma unroll
        for (int it = 0; it < 2; ++it) {
            int fi = tid + it * 256;            // 512 float4s
            int r = fi >> 3, q = fi & 7;
            int row = row0 + r;
            float4 v = make_float4(0.f, 0.f, 0.f, 0.f);
            if (row < n) v = *(const float4*)&X[(size_t)row * K + k0 + q * 4];
            *(float4*)&Xs[r * 36 + q * 4] = v;
        }
#pragma unroll
        for (int it = 0; it < 2; ++it) {
            int fi = tid + it * 256;            // 512 float4s (32*M/4 with M=64)
            int kk = fi >> 4, cw = (fi & 15) * 4;
            float4 w = *(const float4*)&W[(size_t)(k0 + kk) * M + cw];
            if (FOLD) { w.x *= bns[cw]; w.y *= bns[cw + 1]; w.z *= bns[cw + 2]; w.w *= bns[cw + 3]; }
            *(float4*)&Ws[kk * M + cw] = w;
        }
        __syncthreads();
#pragma unroll 8
        for (int kk = 0; kk < KC; ++kk) {
            float4 bv = *(float4*)&Ws[kk * M + tx * 4];
#pragma unroll
            for (int j = 0; j < 4; ++j) {
                float a = Xs[(ty * 4 + j) * 36 + kk];
                acc[j][0] += a * bv.x;
                acc[j][1] += a * bv.y;
                acc[j][2] += a * bv.z;
                acc[j][3] += a * bv.w;
            }
        }
        __syncthreads();
    }
#pragma unroll
    for (int j = 0; j < 4; ++j) {
        int r = row0 + ty * 4 + j;
        if (r < n) {
            float4 v = make_float4(acc[j][0], acc[j][1], acc[j][2], acc[j][3]);
            *(float4*)&Hs[(size_t)r * M + tx * 4] = v;
        }
    }
}

// ---------------- dispatch 2: partition blocks first, then gemm0 blocks ----------------
__global__ __launch_bounds__(256, 4)
void fused_gemm0_partition_kernel(const float* __restrict__ X, const float* __restrict__ W,
                                  const float* __restrict__ gamma, const float* __restrict__ var,
                                  float* __restrict__ Hs, int n,
                                  const int* __restrict__ src, const int* __restrict__ dst,
                                  int* __restrict__ gcur, unsigned int* __restrict__ part,
                                  int nE) {
    __shared__ float lds[64 * 36 + 32 * 64 + 64];   // 17.7 KB
    if (blockIdx.x >= PB) {
        gemm_body<128, 64, true>(blockIdx.x - PB, X, W, gamma, var, Hs, n, lds);
        return;
    }
    // ---- partition branch: bin 4096 edges by dst>>8 ----
    int* lcnt  = (int*)lds;          // 196
    int* gbase = ((int*)lds) + 256;  // 196
    int t = threadIdx.x;
    int base = blockIdx.x * 4096;
    for (int i = t; i < NBUCK; i += 256) lcnt[i] = 0;
    __syncthreads();
    unsigned int val[16], pk[16];
#pragma unroll
    for (int i = 0; i < 16; ++i) {
        int e = base + i * 256 + t;
        if (e < nE) {
            unsigned s = (unsigned)src[e], d = (unsigned)dst[e];
            unsigned b = d >> 8;
            int r = atomicAdd(&lcnt[b], 1);
            val[i] = s | ((d & 255u) << 16);
            pk[i] = b | ((unsigned)r << 8);
        } else pk[i] = 0xffffffffu;
    }
    __syncthreads();
    for (int i = t; i < NBUCK; i += 256) gbase[i] = atomicAdd(&gcur[i], lcnt[i]);
    __syncthreads();
#pragma unroll
    for (int i = 0; i < 16; ++i) {
        if (pk[i] != 0xffffffffu) {
            unsigned b = pk[i] & 255u;
            unsigned p = (unsigned)gbase[b] + (pk[i] >> 8);
            if (p < PART_CAP) part[b * PART_CAP + p] = val[i];
        }
    }
}

// ---------------- dispatch 3: CSR build, 8-PADDED lists + dinv + fp16 table ----------------
// Lists padded to multiples of 8 with PAD_IDX (zero row) -> branch-free 8-deep batches
// (r11: -25us). 1024 thr/bucket (r7: -6.5us). Counting sort by (node, src-phase).
__global__ __launch_bounds__(1024, 1)
void build_kernel(const unsigned int* __restrict__ part, const int* __restrict__ gcur,
                  uint2* __restrict__ rowptr, float* __restrict__ dinv,
                  unsigned short* __restrict__ csr, const float* __restrict__ Hs,
                  __half* __restrict__ Hh, int n) {
    __shared__ int buf[1024];          // scan scratch (reused)
    __shared__ int nc4[1024], cur4[1024];
    __shared__ float sdinv[256];
    __shared__ unsigned short csr_lds[CSR_LDS_CAP];
    __shared__ int sh[2];              // sh[0]=padded base, sh[1]=raw ec
    int b = blockIdx.x, t = threadIdx.x;

    // zero row of Hh (once, block 0): 64 halves = 8 uint4
    if (b == 0 && t < 8) ((uint4*)(Hh + (size_t)PAD_IDX * 64))[t] = make_uint4(0, 0, 0, 0);

    // bucket-offset scan over gcur (raw counts); padded base = align8(raw base) + b*BUCK_STRIDE
    int v = (t < NBUCK) ? gcur[t] : 0;
    int ex = lds_scan_excl<1024>(buf, t, v);
    if (t == b) { sh[0] = ((ex + 7) & ~7) + b * BUCK_STRIDE; sh[1] = v; }
    nc4[t] = 0;
    __syncthreads();
    int base = sh[0];
    int ec = sh[1] < PART_CAP ? sh[1] : PART_CAP;
    const unsigned int* pb = part + (size_t)b * PART_CAP;

    // histogram per (node, phase)
    for (int i = t; i < ec; i += 1024) {
        unsigned w = pb[i];
        atomicAdd(&nc4[((w >> 16) & 255u) * 4 + src_phase(w & 0xffffu)], 1);
    }
    __syncthreads();

    // per-node prefix over PADDED counts (nodes owned by threads 0..255)
    int c = 0, c0 = 0, c1 = 0, c2 = 0, cp = 0;
    if (t < 256) {
        c0 = nc4[t * 4 + 0]; c1 = nc4[t * 4 + 1]; c2 = nc4[t * 4 + 2];
        c = c0 + c1 + c2 + nc4[t * 4 + 3];
        cp = (c + 7) & ~7;
    }
    int nx = lds_scan_excl<1024>(buf, t, cp);
    int ptot = buf[1023];              // padded total of this bucket (valid post-scan)
    if (t < 256) {
        cur4[t * 4 + 0] = nx;
        cur4[t * 4 + 1] = nx + c0;
        cur4[t * 4 + 2] = nx + c0 + c1;
        cur4[t * 4 + 3] = nx + c0 + c1 + c2;
        float dv = rsqrtf((float)c + 1.0f);   // +1 = self loop (raw degree)
        sdinv[t] = dv;
        int node = b * 256 + t;
        if (node < n) {
            rowptr[node] = make_uint2((unsigned)(base + nx), (unsigned)(base + nx + cp));
            dinv[node] = dv;
        }
    }
    __syncthreads();

    // scatter real edges (phase-grouped within node), then fill pad slots with PAD_IDX
    for (int i = t; i < ec; i += 1024) {
        unsigned w = pb[i];
        unsigned nd = (w >> 16) & 255u;
        unsigned s = w & 0xffffu;
        int p = atomicAdd(&cur4[nd * 4 + src_phase(s)], 1);
        csr_lds[p] = (unsigned short)s;
    }
    if (t < 256) {
        for (int i = nx + c; i < nx + cp; ++i) csr_lds[i] = (unsigned short)PAD_IDX;
    }
    __syncthreads();
    for (int i = t; i < ptot; i += 1024) csr[base + i] = csr_lds[i];

    // convert this bucket's Hs rows to fp16 with dinv prefold
    const float4* H4 = (const float4*)(Hs + (size_t)b * 256 * 64);
    for (int i = t; i < 4096; i += 1024) {
        int nd = i >> 4;
        int nn = b * 256 + nd;
        if (nn < n) {
            float s = sdinv[nd];
            float4 x = H4[i];
            union { uint2 u; __half2 h[2]; } U;
            U.h[0] = __floats2half2_rn(x.x * s, x.y * s);
            U.h[1] = __floats2half2_rn(x.z * s, x.w * s);
            *(uint2*)&Hh[(size_t)nn * 64 + (i & 15) * 4] = U.u;
        }
    }
}

// ---------------- fused gather (fp16 table, BN+ReLU) + next-layer GEMM ----------------
// block = 32 nodes x 8 lanes; lane owns 8 channels (16B fp16 loads).
// PAIRED SOFTWARE PIPELINE: csr loads ivA,ivB issued FIRST (in-order vmcnt releases
// ivB at vmcnt(8), keeping vA rows in flight), then all 16 row loads, then ACC A, ACC B.
// Steady in-flight per thread 8->16. Accumulation order identical to sequential batches.
// launch_bounds (256,4)=128 VGPR: vA+vB=64 live regs need headroom (r10: cap-riding
// strangled MLP, -14.5us when relaxed; never sit on the cap).
template <int MOUT, bool FOLD_NEXT>
__global__ __launch_bounds__(256, 4)
void gather_gemm_h(const __half* __restrict__ Hh, const uint2* __restrict__ rowptr,
                   const unsigned short* __restrict__ csr, const float* __restrict__ dinv,
                   const float* __restrict__ bb, const float* __restrict__ gamma,
                   const float* __restrict__ beta, const float* __restrict__ mean,
                   const float* __restrict__ var,
                   const float* __restrict__ Wn, const float* __restrict__ gn,
                   const float* __restrict__ vn, __half* __restrict__ Hout, int n) {
    __shared__ float zs[32 * 68];          // pad 68: conflict-free b128 broadcast per node
    __shared__ float Ws[64 * MOUT];
    int t = threadIdx.x;
    int nd = t >> 3, l = t & 7;
    int d = blockIdx.x * 32 + nd;
    int c8 = l * 8;
    // zero row of Hout (once): pad rows of the NEXT gather read this
    if (blockIdx.x == 0 && t < MOUT) Hout[(size_t)PAD_IDX * MOUT + t] = __float2half(0.f);
    // stage next-layer W (BN-fold if requested); barrier BEFORE the long gather phase
    for (int i = t; i < 64 * MOUT; i += 256) {
        float w = Wn[i];
        if (FOLD_NEXT) { int c = i % MOUT; w *= gn[c] * rsqrtf(vn[c] + BN_EPS); }
        Ws[i] = w;
    }
    __syncthreads();
    float acc[8] = {};
    float di = 0.f;
    int e = 0, end = 0;
    if (d < n) {
        uint2 rp = rowptr[d];
        e = (int)rp.x; end = (int)rp.y;
        di = dinv[d];
        union { uint4 u; __half2 h[4]; } S;
        S.u = *(const uint4*)&Hh[(size_t)d * 64 + c8];   // self loop (prescaled)
#pragma unroll
        for (int p = 0; p < 4; ++p) {
            float2 f = __half22float2(S.h[p]);
            acc[2 * p] += f.x; acc[2 * p + 1] += f.y;
        }
    }
    int rem = end - e;                     // multiple of 8
    uint4 vA[8], vB[8];
    for (; rem >= 16; rem -= 16, e += 16) {
        uint4 ivA = *(const uint4*)&csr[e];
        uint4 ivB = *(const uint4*)&csr[e + 8];
        issue8<64>(Hh, ivA, c8, vA);
        issue8<64>(Hh, ivB, c8, vB);
        acc8(vA, acc);
        acc8(vB, acc);
    }
    if (rem > 0) {
        uint4 iv = *(const uint4*)&csr[e];
        issue8<64>(Hh, iv, c8, vA);
        acc8(vA, acc);
    }
    // BN bias + ReLU of current layer, write z tile to LDS (own wave's rows only)
    if (d < n) {
#pragma unroll
        for (int q = 0; q < 8; ++q) {
            int cc = c8 + q;
            float s0 = gamma[cc] * rsqrtf(var[cc] + BN_EPS);
            float bias = (bb[cc] - mean[cc]) * s0 + beta[cc];
            zs[nd * 68 + cc] = fmaxf(acc[q] * di + bias, 0.0f);
        }
    }
    // wave-local handoff (gemm reads only own wave's zs rows): drain ds_writes; pin order.
    asm volatile("s_waitcnt lgkmcnt(0)" ::: "memory");
    __builtin_amdgcn_sched_barrier(0);
    // ---- gemm phase: Hout[d, c8..c8+7] = fp16(dinv[d] * sum_k zs[nd][k] * Ws[k][c]) ----
    if (c8 < MOUT && d < n) {
        float o[8] = {};
        for (int k0 = 0; k0 < 64; k0 += 4) {
            float4 zq = *(const float4*)&zs[nd * 68 + k0];
#pragma unroll
            for (int j = 0; j < 4; ++j) {
                float zk = (&zq.x)[j];
                float4 w0 = *(const float4*)&Ws[(k0 + j) * MOUT + c8];
                float4 w1 = *(const float4*)&Ws[(k0 + j) * MOUT + c8 + 4];
                o[0] += zk * w0.x; o[1] += zk * w0.y; o[2] += zk * w0.z; o[3] += zk * w0.w;
                o[4] += zk * w1.x; o[5] += zk * w1.y; o[6] += zk * w1.z; o[7] += zk * w1.w;
            }
        }
        union { uint4 u; __half2 h[4]; } O;
#pragma unroll
        for (int p = 0; p < 4; ++p)
            O.h[p] = __floats2half2_rn(o[2 * p] * di, o[2 * p + 1] * di);
        *(uint4*)&Hout[(size_t)d * MOUT + c8] = O.u;
    }
}

// ---------------- final gather over fp16 40-ch rows; fp32 out ----------------
// block = 50 nodes x 5 lanes (250 active); lane owns 8 channels. Paired pipeline as d4/d5.
// launch_bounds (256,5)=102 VGPR: simpler body (~85-90 live) keeps headroom at 5 blocks.
__global__ __launch_bounds__(256, 5)
void gather_out_kernel(const __half* __restrict__ t3, const uint2* __restrict__ rowptr,
                       const unsigned short* __restrict__ csr, const float* __restrict__ dinv,
                       const float* __restrict__ bias, float* __restrict__ out, int n) {
    int t = threadIdx.x;
    if (t >= 250) return;
    int nd = t / 5, l = t % 5;
    int d = blockIdx.x * 50 + nd;
    if (d >= n) return;
    int c8 = l * 8;
    uint2 rp = rowptr[d];
    int e = (int)rp.x, end = (int)rp.y;
    float di = dinv[d];
    float acc[8];
    {
        union { uint4 u; __half2 h[4]; } S;
        S.u = *(const uint4*)&t3[(size_t)d * 40 + c8];
#pragma unroll
        for (int p = 0; p < 4; ++p) {
            float2 f = __half22float2(S.h[p]);
            acc[2 * p] = f.x; acc[2 * p + 1] = f.y;
        }
    }
    int rem = end - e;
    uint4 vA[8], vB[8];
    for (; rem >= 16; rem -= 16, e += 16) {
        uint4 ivA = *(const uint4*)&csr[e];
        uint4 ivB = *(const uint4*)&csr[e + 8];
        issue8<40>(t3, ivA, c8, vA);
        issue8<40>(t3, ivB, c8, vB);
        acc8(vA, acc);
        acc8(vB, acc);
    }
    if (rem > 0) {
        uint4 iv = *(const uint4*)&csr[e];
        issue8<40>(t3, iv, c8, vA);
        acc8(vA, acc);
    }
    float4 r0, r1;
    r0.x = acc[0] * di + bias[c8 + 0];
    r0.y = acc[1] * di + bias[c8 + 1];
    r0.z = acc[2] * di + bias[c8 + 2];
    r0.w = acc[3] * di + bias[c8 + 3];
    r1.x = acc[4] * di + bias[c8 + 4];
    r1.y = acc[5] * di + bias[c8 + 5];
    r1.z = acc[6] * di + bias[c8 + 6];
    r1.w = acc[7] * di + bias[c8 + 7];
    *(float4*)&out[(size_t)d * 40 + c8] = r0;
    *(float4*)&out[(size_t)d * 40 + c8 + 4] = r1;
}

extern "C" void kernel_launch(void* const* d_in, const int* in_sizes, int n_in,
                              void* d_out, int out_size, void* d_ws, size_t ws_size,
                              hipStream_t stream) {
    const float* x      = (const float*)d_in[0];
    const int*   ei     = (const int*)d_in[1];
    const float* W0     = (const float*)d_in[2];
    const float* b0     = (const float*)d_in[3];
    const float* gamma0 = (const float*)d_in[4];
    const float* beta0  = (const float*)d_in[5];
    const float* mean0  = (const float*)d_in[6];
    const float* var0   = (const float*)d_in[7];
    const float* W1     = (const float*)d_in[8];
    const float* b1     = (const float*)d_in[9];
    const float* gamma1 = (const float*)d_in[10];
    const float* beta1  = (const float*)d_in[11];
    const float* mean1  = (const float*)d_in[12];
    const float* var1   = (const float*)d_in[13];
    const float* W2     = (const float*)d_in[14];
    const float* b2     = (const float*)d_in[15];
    float* out = (float*)d_out;

    const int* srcp = ei;
    const int* dstp = ei + N_EDGES;
    const int N = N_NODES, E = N_EDGES;

    // workspace carve-up (bytes, 128-aligned). Total 26.9 MB.
    char* ws = (char*)d_ws;
    int*            gcur   = (int*)(ws + 0);            // 784 B
    uint2*          rowptr = (uint2*)(ws + 1024);       // 400 KB (beg,end per node)
    float*          dinv   = (float*)(ws + 401152);     // 200 KB
    unsigned short* csr    = (unsigned short*)(ws + 601344);   // 2.3 MB (8-padded lists)
    float*          Hs     = (float*)(ws + 2960896);    // 12.8 MB fp32 gemm0 out (dead after d3)
    __half*         bufh   = (__half*)(ws + 2960896);   // 6.4 MB+row, aliases Hs (written d4)
    __half*         t3h    = (__half*)(ws + 9361152);   // 4.0 MB+row (written d5)
    unsigned int*   part   = (unsigned int*)(ws + 15761152);   // 4.7 MB (dead after d3)
    __half*         Hh     = (__half*)(ws + 20477952);  // 6.4 MB+row fp16 prescaled table

    hipMemsetAsync(gcur, 0, NBUCK * sizeof(int), stream);

    // d2: partition (blocks 0..195) + gemm0 (BN0-folded, 64-row tiles) in one dispatch
    fused_gemm0_partition_kernel<<<PB + GB, 256, 0, stream>>>(
        x, W0, gamma0, var0, Hs, N, srcp, dstp, gcur, part, E);

    // d3: CSR build (8-padded, zero-row pads) + rowptr(beg,end) + dinv + fp16 table Hh
    build_kernel<<<NBUCK, 1024, 0, stream>>>(part, gcur, rowptr, dinv, csr, Hs, Hh, N);

    // d4: gather layer0 (fp16 rows, BN0 bias+relu) + gemm1 (BN1-scale folded) -> bufh (fp16)
    gather_gemm_h<64, true><<<(N + 31) / 32, 256, 0, stream>>>(
        Hh, rowptr, csr, dinv, b0, gamma0, beta0, mean0, var0,
        W1, gamma1, var1, bufh, N);

    // d5: gather layer1 (fp16 rows, BN1 bias+relu) + gemm2 (raw W2) -> t3h (fp16, 40ch)
    gather_gemm_h<40, false><<<(N + 31) / 32, 256, 0, stream>>>(
        bufh, rowptr, csr, dinv, b1, gamma1, beta1, mean1, var1,
        W2, nullptr, nullptr, t3h, N);

    // d6: final gather over t3h + b2 -> fp32 out
    gather_out_kernel<<<N / 50, 256, 0, stream>>>(t3h, rowptr, csr, dinv, b2, out, N);
}

// Round 14
// 182.325 us; speedup vs baseline: 1.0168x; 1.0168x over previous
//
#include <hip/hip_runtime.h>
#include <hip/hip_fp16.h>

#define N_NODES 50000
#define N_EDGES 800000
#define BN_EPS 1e-5f

#define NBUCK 196        // ceil(50000/256) buckets of 256 nodes
#define PART_CAP 6016    // per-bucket raw capacity; mean 4082, sd 64 -> 30 sigma margin
#define BUCK_STRIDE 1800 // per-bucket pad allowance: 256 nodes * 7 max pad, 8-aligned, +slack
#define CSR_LDS_CAP 7808 // PART_CAP + 256*7
#define PAD_IDX 50000    // dummy src index -> zero row appended to each gather table
#define PB 196           // partition blocks (ceil(800000/4096))
#define GB 782           // gemm0 blocks (ceil(50000/64), 64-row tiles)

typedef _Float16 f16x8 __attribute__((ext_vector_type(8)));
typedef _Float16 f16x4 __attribute__((ext_vector_type(4)));
typedef float f32x4 __attribute__((ext_vector_type(4)));

// exclusive WIDTH-thread scan in LDS; s[] is scratch (WIDTH ints). All WIDTH threads call.
// After return, s[WIDTH-1] holds the inclusive total (valid until s is rewritten).
template <int WIDTH>
__device__ __forceinline__ int lds_scan_excl(int* s, int t, int v) {
    s[t] = v;
    __syncthreads();
    for (int off = 1; off < WIDTH; off <<= 1) {
        int x = (t >= off) ? s[t - off] : 0;
        __syncthreads();
        s[t] += x;
        __syncthreads();
    }
    return s[t] - v;
}

// phase of a source node id (4 ranges of 12500); exact floor(s/12500) for s<50000
__device__ __forceinline__ unsigned src_phase(unsigned s) {
    return (s * 42950u) >> 29;
}

// issue 8 row loads (16B each) for the 8 indices packed in iv
template <int LD>
__device__ __forceinline__ void issue8(const __half* __restrict__ T, uint4 iv, int c8,
                                       uint4* vv) {
    int s0 = iv.x & 0xffff, s1 = iv.x >> 16;
    int s2 = iv.y & 0xffff, s3 = iv.y >> 16;
    int s4 = iv.z & 0xffff, s5 = iv.z >> 16;
    int s6 = iv.w & 0xffff, s7 = iv.w >> 16;
    vv[0] = *(const uint4*)&T[(size_t)s0 * LD + c8];
    vv[1] = *(const uint4*)&T[(size_t)s1 * LD + c8];
    vv[2] = *(const uint4*)&T[(size_t)s2 * LD + c8];
    vv[3] = *(const uint4*)&T[(size_t)s3 * LD + c8];
    vv[4] = *(const uint4*)&T[(size_t)s4 * LD + c8];
    vv[5] = *(const uint4*)&T[(size_t)s5 * LD + c8];
    vv[6] = *(const uint4*)&T[(size_t)s6 * LD + c8];
    vv[7] = *(const uint4*)&T[(size_t)s7 * LD + c8];
}

__device__ __forceinline__ void acc8(const uint4* vv, float* acc) {
#pragma unroll
    for (int q = 0; q < 8; ++q) {
        union { uint4 u; __half2 h[4]; } V; V.u = vv[q];
#pragma unroll
        for (int p = 0; p < 4; ++p) {
            float2 f = __half22float2(V.h[p]);
            acc[2 * p] += f.x; acc[2 * p + 1] += f.y;
        }
    }
}

// ---------------- MFMA GEMM0 body: Hs[r,64] = fp16(X[r,128]) @ fp16(W0 .* bn0scale) ----
// 64-row tile, 4 waves x 16-row stripes, mfma_f32_16x16x32_f16 (fp32 accum).
// Layout facts used (doc-verified m89/m91): A row = lane&15, B col = lane&15,
// D: col=lane&15, row=(lane>>4)*4+reg. K-slot mapping CANCELS: A-slot(g,j)=X[m][f],
// B-slot(g,j)=W[f][n] with the same f=(g*8+j) sums all 32 k regardless of HW's slot->k.
// Wt stored transposed [col][k] stride 136 -> b128 frag reads, 2-way conflicts only.
// (r6 lesson: keep this a separate small kernel body, not mega-fused.)
__device__ __forceinline__ void gemm0_mfma_body(int bid, const float* __restrict__ X,
                                                const float* __restrict__ W,
                                                const float* __restrict__ gamma,
                                                const float* __restrict__ var,
                                                float* __restrict__ Hs, int n, char* smem) {
    _Float16* Xs = (_Float16*)smem;             // 64 x 136 (pad: 2-way only)
    _Float16* Wt = (_Float16*)(smem + 17408);   // 64 cols x 136 k
    float* bns = (float*)(smem + 34816);        // 64 bn scales
    const int tid = threadIdx.x;
    const int row0 = bid * 64;
    if (tid < 64) bns[tid] = gamma[tid] * rsqrtf(var[tid] + BN_EPS);
    __syncthreads();
    // stage X tile 64x128 fp32 -> fp16 (zero-pad rows >= n)
#pragma unroll
    for (int it = 0; it < 8; ++it) {
        int fi = tid + it * 256;                // 2048 float4s
        int r = fi >> 5, c4 = (fi & 31) * 4;
        int row = row0 + r;
        float4 v = make_float4(0.f, 0.f, 0.f, 0.f);
        if (row < n) v = *(const float4*)&X[(size_t)row * 128 + c4];
        f16x4 h;
        h[0] = (_Float16)v.x; h[1] = (_Float16)v.y;
        h[2] = (_Float16)v.z; h[3] = (_Float16)v.w;
        *(f16x4*)&Xs[r * 136 + c4] = h;
    }
    // stage W 128x64 fp32 -> bn-folded fp16, TRANSPOSED into Wt[col][k]
#pragma unroll
    for (int it = 0; it < 8; ++it) {
        int fi = tid + it * 256;                // 2048 float4s
        int k = fi >> 4, c4 = (fi & 15) * 4;
        float4 w = *(const float4*)&W[(size_t)k * 64 + c4];
        Wt[(c4 + 0) * 136 + k] = (_Float16)(w.x * bns[c4 + 0]);
        Wt[(c4 + 1) * 136 + k] = (_Float16)(w.y * bns[c4 + 1]);
        Wt[(c4 + 2) * 136 + k] = (_Float16)(w.z * bns[c4 + 2]);
        Wt[(c4 + 3) * 136 + k] = (_Float16)(w.w * bns[c4 + 3]);
    }
    __syncthreads();
    const int wv = tid >> 6, lane = tid & 63;
    const int lrow = lane & 15, lgrp = lane >> 4;
    f16x8 a[4];
#pragma unroll
    for (int ks = 0; ks < 4; ++ks)
        a[ks] = *(f16x8*)&Xs[(wv * 16 + lrow) * 136 + ks * 32 + lgrp * 8];
    f32x4 acc[4] = {};
#pragma unroll
    for (int nt = 0; nt < 4; ++nt) {
#pragma unroll
        for (int ks = 0; ks < 4; ++ks) {
            f16x8 b = *(f16x8*)&Wt[(nt * 16 + lrow) * 136 + ks * 32 + lgrp * 8];
            acc[nt] = __builtin_amdgcn_mfma_f32_16x16x32_f16(a[ks], b, acc[nt], 0, 0, 0);
        }
    }
    // store: D row = lgrp*4 + r, col = lrow (within wave stripe / n-tile)
#pragma unroll
    for (int nt = 0; nt < 4; ++nt) {
#pragma unroll
        for (int r = 0; r < 4; ++r) {
            int row = row0 + wv * 16 + lgrp * 4 + r;
            if (row < n) Hs[(size_t)row * 64 + nt * 16 + lrow] = acc[nt][r];
        }
    }
}

// ---------------- dispatch 2: partition blocks first, then gemm0 blocks ----------------
__global__ __launch_bounds__(256, 4)
void fused_gemm0_partition_kernel(const float* __restrict__ X, const float* __restrict__ W,
                                  const float* __restrict__ gamma, const float* __restrict__ var,
                                  float* __restrict__ Hs, int n,
                                  const int* __restrict__ src, const int* __restrict__ dst,
                                  int* __restrict__ gcur, unsigned int* __restrict__ part,
                                  int nE) {
    __shared__ __align__(16) char smem[35072];   // 34.3 KB; x4 blocks = 137 KB/CU
    if (blockIdx.x >= PB) {
        gemm0_mfma_body(blockIdx.x - PB, X, W, gamma, var, Hs, n, smem);
        return;
    }
    // ---- partition branch: bin 4096 edges by dst>>8 ----
    int* lcnt  = (int*)smem;          // 196
    int* gbase = ((int*)smem) + 256;  // 196
    int t = threadIdx.x;
    int base = blockIdx.x * 4096;
    for (int i = t; i < NBUCK; i += 256) lcnt[i] = 0;
    __syncthreads();
    unsigned int val[16], pk[16];
#pragma unroll
    for (int i = 0; i < 16; ++i) {
        int e = base + i * 256 + t;
        if (e < nE) {
            unsigned s = (unsigned)src[e], d = (unsigned)dst[e];
            unsigned b = d >> 8;
            int r = atomicAdd(&lcnt[b], 1);
            val[i] = s | ((d & 255u) << 16);
            pk[i] = b | ((unsigned)r << 8);
        } else pk[i] = 0xffffffffu;
    }
    __syncthreads();
    for (int i = t; i < NBUCK; i += 256) gbase[i] = atomicAdd(&gcur[i], lcnt[i]);
    __syncthreads();
#pragma unroll
    for (int i = 0; i < 16; ++i) {
        if (pk[i] != 0xffffffffu) {
            unsigned b = pk[i] & 255u;
            unsigned p = (unsigned)gbase[b] + (pk[i] >> 8);
            if (p < PART_CAP) part[b * PART_CAP + p] = val[i];
        }
    }
}

// ---------------- dispatch 3: CSR build, 8-PADDED lists + dinv + fp16 table ----------------
// Lists padded to multiples of 8 with PAD_IDX (zero row) -> branch-free 8-deep batches
// (r11: -25us). 1024 thr/bucket (r7: -6.5us). Counting sort by (node, src-phase).
__global__ __launch_bounds__(1024, 1)
void build_kernel(const unsigned int* __restrict__ part, const int* __restrict__ gcur,
                  uint2* __restrict__ rowptr, float* __restrict__ dinv,
                  unsigned short* __restrict__ csr, const float* __restrict__ Hs,
                  __half* __restrict__ Hh, int n) {
    __shared__ int buf[1024];          // scan scratch (reused)
    __shared__ int nc4[1024], cur4[1024];
    __shared__ float sdinv[256];
    __shared__ unsigned short csr_lds[CSR_LDS_CAP];
    __shared__ int sh[2];              // sh[0]=padded base, sh[1]=raw ec
    int b = blockIdx.x, t = threadIdx.x;

    // zero row of Hh (once, block 0): 64 halves = 8 uint4
    if (b == 0 && t < 8) ((uint4*)(Hh + (size_t)PAD_IDX * 64))[t] = make_uint4(0, 0, 0, 0);

    // bucket-offset scan over gcur (raw counts); padded base = align8(raw base) + b*BUCK_STRIDE
    int v = (t < NBUCK) ? gcur[t] : 0;
    int ex = lds_scan_excl<1024>(buf, t, v);
    if (t == b) { sh[0] = ((ex + 7) & ~7) + b * BUCK_STRIDE; sh[1] = v; }
    nc4[t] = 0;
    __syncthreads();
    int base = sh[0];
    int ec = sh[1] < PART_CAP ? sh[1] : PART_CAP;
    const unsigned int* pb = part + (size_t)b * PART_CAP;

    // histogram per (node, phase)
    for (int i = t; i < ec; i += 1024) {
        unsigned w = pb[i];
        atomicAdd(&nc4[((w >> 16) & 255u) * 4 + src_phase(w & 0xffffu)], 1);
    }
    __syncthreads();

    // per-node prefix over PADDED counts (nodes owned by threads 0..255)
    int c = 0, c0 = 0, c1 = 0, c2 = 0, cp = 0;
    if (t < 256) {
        c0 = nc4[t * 4 + 0]; c1 = nc4[t * 4 + 1]; c2 = nc4[t * 4 + 2];
        c = c0 + c1 + c2 + nc4[t * 4 + 3];
        cp = (c + 7) & ~7;
    }
    int nx = lds_scan_excl<1024>(buf, t, cp);
    int ptot = buf[1023];              // padded total of this bucket (valid post-scan)
    if (t < 256) {
        cur4[t * 4 + 0] = nx;
        cur4[t * 4 + 1] = nx + c0;
        cur4[t * 4 + 2] = nx + c0 + c1;
        cur4[t * 4 + 3] = nx + c0 + c1 + c2;
        float dv = rsqrtf((float)c + 1.0f);   // +1 = self loop (raw degree)
        sdinv[t] = dv;
        int node = b * 256 + t;
        if (node < n) {
            rowptr[node] = make_uint2((unsigned)(base + nx), (unsigned)(base + nx + cp));
            dinv[node] = dv;
        }
    }
    __syncthreads();

    // scatter real edges (phase-grouped within node), then fill pad slots with PAD_IDX
    for (int i = t; i < ec; i += 1024) {
        unsigned w = pb[i];
        unsigned nd = (w >> 16) & 255u;
        unsigned s = w & 0xffffu;
        int p = atomicAdd(&cur4[nd * 4 + src_phase(s)], 1);
        csr_lds[p] = (unsigned short)s;
    }
    if (t < 256) {
        for (int i = nx + c; i < nx + cp; ++i) csr_lds[i] = (unsigned short)PAD_IDX;
    }
    __syncthreads();
    for (int i = t; i < ptot; i += 1024) csr[base + i] = csr_lds[i];

    // convert this bucket's Hs rows to fp16 with dinv prefold
    const float4* H4 = (const float4*)(Hs + (size_t)b * 256 * 64);
    for (int i = t; i < 4096; i += 1024) {
        int nd = i >> 4;
        int nn = b * 256 + nd;
        if (nn < n) {
            float s = sdinv[nd];
            float4 x = H4[i];
            union { uint2 u; __half2 h[2]; } U;
            U.h[0] = __floats2half2_rn(x.x * s, x.y * s);
            U.h[1] = __floats2half2_rn(x.z * s, x.w * s);
            *(uint2*)&Hh[(size_t)nn * 64 + (i & 15) * 4] = U.u;
        }
    }
}

// ---------------- fused gather (fp16 table, BN+ReLU) + next-layer GEMM ----------------
// block = 32 nodes x 8 lanes; lane owns 8 channels (16B fp16 loads). Paired 16-deep issue
// (r13: neutral vs 8-deep -- CU vmem queue saturated; kept, bit-identical semantics).
// launch_bounds (256,4)=128 VGPR (r10: cap-riding strangled MLP; never sit on the cap).
template <int MOUT, bool FOLD_NEXT>
__global__ __launch_bounds__(256, 4)
void gather_gemm_h(const __half* __restrict__ Hh, const uint2* __restrict__ rowptr,
                   const unsigned short* __restrict__ csr, const float* __restrict__ dinv,
                   const float* __restrict__ bb, const float* __restrict__ gamma,
                   const float* __restrict__ beta, const float* __restrict__ mean,
                   const float* __restrict__ var,
                   const float* __restrict__ Wn, const float* __restrict__ gn,
                   const float* __restrict__ vn, __half* __restrict__ Hout, int n) {
    __shared__ float zs[32 * 68];          // pad 68: conflict-free b128 broadcast per node
    __shared__ float Ws[64 * MOUT];
    int t = threadIdx.x;
    int nd = t >> 3, l = t & 7;
    int d = blockIdx.x * 32 + nd;
    int c8 = l * 8;
    // zero row of Hout (once): pad rows of the NEXT gather read this
    if (blockIdx.x == 0 && t < MOUT) Hout[(size_t)PAD_IDX * MOUT + t] = __float2half(0.f);
    // stage next-layer W (BN-fold if requested); barrier BEFORE the long gather phase
    for (int i = t; i < 64 * MOUT; i += 256) {
        float w = Wn[i];
        if (FOLD_NEXT) { int c = i % MOUT; w *= gn[c] * rsqrtf(vn[c] + BN_EPS); }
        Ws[i] = w;
    }
    __syncthreads();
    float acc[8] = {};
    float di = 0.f;
    int e = 0, end = 0;
    if (d < n) {
        uint2 rp = rowptr[d];
        e = (int)rp.x; end = (int)rp.y;
        di = dinv[d];
        union { uint4 u; __half2 h[4]; } S;
        S.u = *(const uint4*)&Hh[(size_t)d * 64 + c8];   // self loop (prescaled)
#pragma unroll
        for (int p = 0; p < 4; ++p) {
            float2 f = __half22float2(S.h[p]);
            acc[2 * p] += f.x; acc[2 * p + 1] += f.y;
        }
    }
    int rem = end - e;                     // multiple of 8
    uint4 vA[8], vB[8];
    for (; rem >= 16; rem -= 16, e += 16) {
        uint4 ivA = *(const uint4*)&csr[e];
        uint4 ivB = *(const uint4*)&csr[e + 8];
        issue8<64>(Hh, ivA, c8, vA);
        issue8<64>(Hh, ivB, c8, vB);
        acc8(vA, acc);
        acc8(vB, acc);
    }
    if (rem > 0) {
        uint4 iv = *(const uint4*)&csr[e];
        issue8<64>(Hh, iv, c8, vA);
        acc8(vA, acc);
    }
    // BN bias + ReLU of current layer, write z tile to LDS (own wave's rows only)
    if (d < n) {
#pragma unroll
        for (int q = 0; q < 8; ++q) {
            int cc = c8 + q;
            float s0 = gamma[cc] * rsqrtf(var[cc] + BN_EPS);
            float bias = (bb[cc] - mean[cc]) * s0 + beta[cc];
            zs[nd * 68 + cc] = fmaxf(acc[q] * di + bias, 0.0f);
        }
    }
    // wave-local handoff (gemm reads only own wave's zs rows): drain ds_writes; pin order.
    asm volatile("s_waitcnt lgkmcnt(0)" ::: "memory");
    __builtin_amdgcn_sched_barrier(0);
    // ---- gemm phase: Hout[d, c8..c8+7] = fp16(dinv[d] * sum_k zs[nd][k] * Ws[k][c]) ----
    if (c8 < MOUT && d < n) {
        float o[8] = {};
        for (int k0 = 0; k0 < 64; k0 += 4) {
            float4 zq = *(const float4*)&zs[nd * 68 + k0];
#pragma unroll
            for (int j = 0; j < 4; ++j) {
                float zk = (&zq.x)[j];
                float4 w0 = *(const float4*)&Ws[(k0 + j) * MOUT + c8];
                float4 w1 = *(const float4*)&Ws[(k0 + j) * MOUT + c8 + 4];
                o[0] += zk * w0.x; o[1] += zk * w0.y; o[2] += zk * w0.z; o[3] += zk * w0.w;
                o[4] += zk * w1.x; o[5] += zk * w1.y; o[6] += zk * w1.z; o[7] += zk * w1.w;
            }
        }
        union { uint4 u; __half2 h[4]; } O;
#pragma unroll
        for (int p = 0; p < 4; ++p)
            O.h[p] = __floats2half2_rn(o[2 * p] * di, o[2 * p + 1] * di);
        *(uint4*)&Hout[(size_t)d * MOUT + c8] = O.u;
    }
}

// ---------------- final gather over fp16 40-ch rows; fp32 out ----------------
// block = 50 nodes x 5 lanes (250 active); lane owns 8 channels. Paired pipeline as d4/d5.
// launch_bounds (256,5)=102 VGPR: simpler body (~85-90 live) keeps headroom at 5 blocks.
__global__ __launch_bounds__(256, 5)
void gather_out_kernel(const __half* __restrict__ t3, const uint2* __restrict__ rowptr,
                       const unsigned short* __restrict__ csr, const float* __restrict__ dinv,
                       const float* __restrict__ bias, float* __restrict__ out, int n) {
    int t = threadIdx.x;
    if (t >= 250) return;
    int nd = t / 5, l = t % 5;
    int d = blockIdx.x * 50 + nd;
    if (d >= n) return;
    int c8 = l * 8;
    uint2 rp = rowptr[d];
    int e = (int)rp.x, end = (int)rp.y;
    float di = dinv[d];
    float acc[8];
    {
        union { uint4 u; __half2 h[4]; } S;
        S.u = *(const uint4*)&t3[(size_t)d * 40 + c8];
#pragma unroll
        for (int p = 0; p < 4; ++p) {
            float2 f = __half22float2(S.h[p]);
            acc[2 * p] = f.x; acc[2 * p + 1] = f.y;
        }
    }
    int rem = end - e;
    uint4 vA[8], vB[8];
    for (; rem >= 16; rem -= 16, e += 16) {
        uint4 ivA = *(const uint4*)&csr[e];
        uint4 ivB = *(const uint4*)&csr[e + 8];
        issue8<40>(t3, ivA, c8, vA);
        issue8<40>(t3, ivB, c8, vB);
        acc8(vA, acc);
        acc8(vB, acc);
    }
    if (rem > 0) {
        uint4 iv = *(const uint4*)&csr[e];
        issue8<40>(t3, iv, c8, vA);
        acc8(vA, acc);
    }
    float4 r0, r1;
    r0.x = acc[0] * di + bias[c8 + 0];
    r0.y = acc[1] * di + bias[c8 + 1];
    r0.z = acc[2] * di + bias[c8 + 2];
    r0.w = acc[3] * di + bias[c8 + 3];
    r1.x = acc[4] * di + bias[c8 + 4];
    r1.y = acc[5] * di + bias[c8 + 5];
    r1.z = acc[6] * di + bias[c8 + 6];
    r1.w = acc[7] * di + bias[c8 + 7];
    *(float4*)&out[(size_t)d * 40 + c8] = r0;
    *(float4*)&out[(size_t)d * 40 + c8 + 4] = r1;
}

extern "C" void kernel_launch(void* const* d_in, const int* in_sizes, int n_in,
                              void* d_out, int out_size, void* d_ws, size_t ws_size,
                              hipStream_t stream) {
    const float* x      = (const float*)d_in[0];
    const int*   ei     = (const int*)d_in[1];
    const float* W0     = (const float*)d_in[2];
    const float* b0     = (const float*)d_in[3];
    const float* gamma0 = (const float*)d_in[4];
    const float* beta0  = (const float*)d_in[5];
    const float* mean0  = (const float*)d_in[6];
    const float* var0   = (const float*)d_in[7];
    const float* W1     = (const float*)d_in[8];
    const float* b1     = (const float*)d_in[9];
    const float* gamma1 = (const float*)d_in[10];
    const float* beta1  = (const float*)d_in[11];
    const float* mean1  = (const float*)d_in[12];
    const float* var1   = (const float*)d_in[13];
    const float* W2     = (const float*)d_in[14];
    const float* b2     = (const float*)d_in[15];
    float* out = (float*)d_out;

    const int* srcp = ei;
    const int* dstp = ei + N_EDGES;
    const int N = N_NODES, E = N_EDGES;

    // workspace carve-up (bytes, 128-aligned). Total 26.9 MB.
    char* ws = (char*)d_ws;
    int*            gcur   = (int*)(ws + 0);            // 784 B
    uint2*          rowptr = (uint2*)(ws + 1024);       // 400 KB (beg,end per node)
    float*          dinv   = (float*)(ws + 401152);     // 200 KB
    unsigned short* csr    = (unsigned short*)(ws + 601344);   // 2.3 MB (8-padded lists)
    float*          Hs     = (float*)(ws + 2960896);    // 12.8 MB fp32 gemm0 out (dead after d3)
    __half*         bufh   = (__half*)(ws + 2960896);   // 6.4 MB+row, aliases Hs (written d4)
    __half*         t3h    = (__half*)(ws + 9361152);   // 4.0 MB+row (written d5)
    unsigned int*   part   = (unsigned int*)(ws + 15761152);   // 4.7 MB (dead after d3)
    __half*         Hh     = (__half*)(ws + 20477952);  // 6.4 MB+row fp16 prescaled table

    hipMemsetAsync(gcur, 0, NBUCK * sizeof(int), stream);

    // d2: partition (blocks 0..195) + gemm0 (fp16 MFMA, BN0-folded) in one dispatch
    fused_gemm0_partition_kernel<<<PB + GB, 256, 0, stream>>>(
        x, W0, gamma0, var0, Hs, N, srcp, dstp, gcur, part, E);

    // d3: CSR build (8-padded, zero-row pads) + rowptr(beg,end) + dinv + fp16 table Hh
    build_kernel<<<NBUCK, 1024, 0, stream>>>(part, gcur, rowptr, dinv, csr, Hs, Hh, N);

    // d4: gather layer0 (fp16 rows, BN0 bias+relu) + gemm1 (BN1-scale folded) -> bufh (fp16)
    gather_gemm_h<64, true><<<(N + 31) / 32, 256, 0, stream>>>(
        Hh, rowptr, csr, dinv, b0, gamma0, beta0, mean0, var0,
        W1, gamma1, var1, bufh, N);

    // d5: gather layer1 (fp16 rows, BN1 bias+relu) + gemm2 (raw W2) -> t3h (fp16, 40ch)
    gather_gemm_h<40, false><<<(N + 31) / 32, 256, 0, stream>>>(
        bufh, rowptr, csr, dinv, b1, gamma1, beta1, mean1, var1,
        W2, nullptr, nullptr, t3h, N);

    // d6: final gather over t3h + b2 -> fp32 out
    gather_out_kernel<<<N / 50, 256, 0, stream>>>(t3h, rowptr, csr, dinv, b2, out, N);
}